// Round 1
// baseline (511.665 us; speedup 1.0000x reference)
//
#include <hip/hip_runtime.h>
#include <hip/hip_bf16.h>

typedef __attribute__((ext_vector_type(8))) short short8;
typedef __attribute__((ext_vector_type(8))) unsigned short u16x8;
typedef __attribute__((ext_vector_type(4))) float f32x4;
typedef unsigned int u32;

#define S_TOK 8192
#define MDIM  1024
#define NEXP  8
#define HDIM  4096
#define CAP   2048   // TOP_K * ceil(S/E) * CF = 2*1024

__device__ __forceinline__ void gll16(const void* g, void* l) {
  __builtin_amdgcn_global_load_lds((const __attribute__((address_space(1))) u32*)g,
                                   (__attribute__((address_space(3))) u32*)l, 16, 0, 0);
}

// ---------------- gate: logits, softmax, top-2, normalized gates ----------------
__global__ __launch_bounds__(256) void gate_kernel(
    const float* __restrict__ x, const float* __restrict__ wg,
    float* __restrict__ gates_full, int* __restrict__ topk, float* __restrict__ gnorm)
{
  __shared__ __align__(16) float swg[NEXP * MDIM];
  const int tid = threadIdx.x;
  #pragma unroll
  for (int i = 0; i < 8; ++i) {
    int idx = tid + i * 256;   // 2048 float4 = 8192 floats
    ((float4*)swg)[idx] = ((const float4*)wg)[idx];
  }
  __syncthreads();
  const int w = tid >> 6, l = tid & 63;
  const int s = blockIdx.x * 4 + w;
  const float* xr = x + (size_t)s * MDIM;
  float a[8] = {0,0,0,0,0,0,0,0};
  for (int j = 0; j < 16; ++j) {
    float xv = xr[l + j * 64];
    #pragma unroll
    for (int e = 0; e < 8; ++e) a[e] += xv * swg[e * MDIM + l + j * 64];
  }
  #pragma unroll
  for (int e = 0; e < 8; ++e)
    #pragma unroll
    for (int off = 32; off > 0; off >>= 1)
      a[e] += __shfl_xor(a[e], off);
  if (l == 0) {
    float m = a[0]; int i1 = 0;
    #pragma unroll
    for (int e = 1; e < 8; ++e) if (a[e] > m) { m = a[e]; i1 = e; }
    float den = 0.f, g[8];
    #pragma unroll
    for (int e = 0; e < 8; ++e) { g[e] = __expf(a[e] - m); den += g[e]; }
    float inv = 1.f / den;
    float m2 = -3.4e38f; int i2 = 0;
    #pragma unroll
    for (int e = 0; e < 8; ++e) if (e != i1 && a[e] > m2) { m2 = a[e]; i2 = e; }
    #pragma unroll
    for (int e = 0; e < 8; ++e) gates_full[(size_t)s * 8 + e] = g[e] * inv;
    float gs1 = inv;                    // exp(0)/den  (top-1 gate)
    float gs2 = __expf(m2 - m) * inv;   // top-2 gate
    float ssum = fmaxf(gs1 + gs2, 1.1920929e-7f);
    topk[s * 2 + 0] = i1; topk[s * 2 + 1] = i2;
    gnorm[s * 2 + 0] = gs1 / ssum; gnorm[s * 2 + 1] = gs2 / ssum;
  }
}

// ---------------- scan: token-order locations, capacity, slot map, l_loss ----------------
__global__ __launch_bounds__(1024) void scan_kernel(
    const int* __restrict__ topk, const float* __restrict__ gnorm,
    const float* __restrict__ gates_full,
    int* __restrict__ gflat, float* __restrict__ gw,
    int* __restrict__ slot2tok, float* __restrict__ lloss)
{
  __shared__ union {
    float mef[8192];
    struct { u16x8 s0[1024]; u16x8 s1[1024]; } sc;
  } sh;
  __shared__ float me_s[8];
  __shared__ int tot_s[8];
  const int t = threadIdx.x;

  #pragma unroll
  for (int i = 0; i < 16; ++i) slot2tok[t + i * 1024] = -1;

  int e1[8], e2[8];
  #pragma unroll
  for (int i = 0; i < 8; ++i) {
    e1[i] = topk[(t * 8 + i) * 2 + 0];
    e2[i] = topk[(t * 8 + i) * 2 + 1];
  }

  // ---- me = sum of full gates per expert ----
  float ms[8] = {0,0,0,0,0,0,0,0};
  for (int i = 0; i < 8; ++i) {
    #pragma unroll
    for (int e = 0; e < 8; ++e) ms[e] += gates_full[(size_t)(t * 8 + i) * 8 + e];
  }
  #pragma unroll
  for (int e = 0; e < 8; ++e) sh.mef[t * 8 + e] = ms[e];
  __syncthreads();
  for (int off = 512; off > 0; off >>= 1) {
    if (t < off) {
      #pragma unroll
      for (int e = 0; e < 8; ++e) sh.mef[t * 8 + e] += sh.mef[(t + off) * 8 + e];
    }
    __syncthreads();
  }
  if (t < 8) me_s[t] = sh.mef[t];
  __syncthreads();

  // ---- per-thread local counts (8 tokens, packed 4-bit) ----
  u32 p0 = 0, p1 = 0;
  #pragma unroll
  for (int i = 0; i < 8; ++i) { p0 += 1u << (4 * e1[i]); p1 += 1u << (4 * e2[i]); }
  union { unsigned short a[8]; u16x8 v; } c0u, c1u;
  #pragma unroll
  for (int e = 0; e < 8; ++e) {
    c0u.a[e] = (unsigned short)((p0 >> (4 * e)) & 15u);
    c1u.a[e] = (unsigned short)((p1 >> (4 * e)) & 15u);
  }
  sh.sc.s0[t] = c0u.v;
  sh.sc.s1[t] = c1u.v;
  __syncthreads();
  // inclusive Hillis-Steele scan over 1024 threads (8-wide vectors)
  for (int off = 1; off < 1024; off <<= 1) {
    u16x8 v0 = (u16x8)(unsigned short)0, v1 = v0;
    const bool p = (t >= off);
    if (p) { v0 = sh.sc.s0[t - off]; v1 = sh.sc.s1[t - off]; }
    __syncthreads();
    if (p) { sh.sc.s0[t] = sh.sc.s0[t] + v0; sh.sc.s1[t] = sh.sc.s1[t] + v1; }
    __syncthreads();
  }
  if (t == 0) {
    u16x8 tv = sh.sc.s0[1023];
    #pragma unroll
    for (int e = 0; e < 8; ++e) tot_s[e] = (int)tv[e];
  }
  __syncthreads();
  // exclusive (own row only; no cross-thread reads after this)
  sh.sc.s0[t] = sh.sc.s0[t] - c0u.v;
  sh.sc.s1[t] = sh.sc.s1[t] - c1u.v;

  const unsigned short* r0 = (const unsigned short*)&sh.sc.s0[t];
  const unsigned short* r1 = (const unsigned short*)&sh.sc.s1[t];
  #pragma unroll
  for (int i = 0; i < 8; ++i) {
    int s = t * 8 + i;
    int cnt0 = 0, cnt1 = 0;
    #pragma unroll
    for (int j = 0; j < 8; ++j) if (j < i) { cnt0 += (e1[j] == e1[i]); cnt1 += (e2[j] == e2[i]); }
    int loc0 = (int)r0[e1[i]] + cnt0;
    int loc1 = tot_s[e2[i]] + (int)r1[e2[i]] + cnt1;
    int v0 = loc0 < CAP, v1 = loc1 < CAP;
    int f0 = e1[i] * CAP + (loc0 < CAP ? loc0 : CAP - 1);
    int f1 = e2[i] * CAP + (loc1 < CAP ? loc1 : CAP - 1);
    gflat[s * 2 + 0] = f0; gflat[s * 2 + 1] = f1;
    float gn0 = gnorm[s * 2 + 0], gn1 = gnorm[s * 2 + 1];
    gw[s * 2 + 0] = v0 ? gn0 : 0.f;
    gw[s * 2 + 1] = v1 ? gn1 : 0.f;
    if (v0) slot2tok[f0] = s;
    if (v1) slot2tok[f1] = s;
  }
  if (t == 0) {
    float ll = 0.f;
    #pragma unroll
    for (int e = 0; e < 8; ++e) ll += me_s[e] * (float)tot_s[e];
    *lloss = ll * ((float)NEXP / ((float)S_TOK * (float)S_TOK));
  }
}

// ---------------- transpose + f32->bf16: in [R][C] -> out [C][R] ----------------
__global__ __launch_bounds__(256) void transpose_cvt_kernel(
    const float* __restrict__ in, __hip_bfloat16* __restrict__ out, int R, int C)
{
  __shared__ float tile[64][68];
  const float* ine = in + (size_t)blockIdx.z * R * C;
  __hip_bfloat16* oute = out + (size_t)blockIdx.z * R * C;
  const int cb = blockIdx.x * 64;
  const int rb = blockIdx.y * 64;
  const int t = threadIdx.x;
  const int rr = t >> 4;
  const int c4 = (t & 15) * 4;
  #pragma unroll
  for (int i = 0; i < 4; ++i) {
    int r = rr + i * 16;
    float4 v = *(const float4*)&ine[(size_t)(rb + r) * C + cb + c4];
    tile[r][c4 + 0] = v.x; tile[r][c4 + 1] = v.y;
    tile[r][c4 + 2] = v.z; tile[r][c4 + 3] = v.w;
  }
  __syncthreads();
  const int oc = t >> 2;
  const int sg = (t & 3) * 16;
  union { unsigned short u[16]; ushort4 v4[4]; } tu;
  #pragma unroll
  for (int j = 0; j < 16; ++j) {
    __hip_bfloat16 b = __float2bfloat16(tile[sg + j][oc]);
    tu.u[j] = *reinterpret_cast<const unsigned short*>(&b);
  }
  ushort4* dst = (ushort4*)&oute[(size_t)(cb + oc) * R + rb + sg];
  #pragma unroll
  for (int q = 0; q < 4; ++q) dst[q] = tu.v4[q];
}

// ---------------- dispatch: gather x rows (f32->bf16) into [E*CAP][M] ----------------
__global__ __launch_bounds__(256) void dispatch_kernel(
    const float* __restrict__ x, const int* __restrict__ slot2tok,
    __hip_bfloat16* __restrict__ dmat)
{
  const int slot = blockIdx.x;
  const int tok = slot2tok[slot];
  const int c = threadIdx.x * 4;
  float4 v = {0.f, 0.f, 0.f, 0.f};
  if (tok >= 0) v = *(const float4*)&x[(size_t)tok * MDIM + c];
  union { unsigned short u[4]; ushort4 v4; } o;
  __hip_bfloat16 b0 = __float2bfloat16(v.x); o.u[0] = *(unsigned short*)&b0;
  __hip_bfloat16 b1 = __float2bfloat16(v.y); o.u[1] = *(unsigned short*)&b1;
  __hip_bfloat16 b2 = __float2bfloat16(v.z); o.u[2] = *(unsigned short*)&b2;
  __hip_bfloat16 b3 = __float2bfloat16(v.w); o.u[3] = *(unsigned short*)&b3;
  *(ushort4*)&dmat[(size_t)slot * MDIM + c] = o.v4;
}

// ---------------- grouped GEMM: C[e] = act(A[e] @ B[e]^T' + bias[e]) ----------------
// A: [E][Mr][K] bf16 row-major; Bt: [E][N][K] bf16 (B pre-transposed, K-contiguous)
// 128x128 tile, BK=32, 4 waves (2x2), mfma 16x16x32, 2-phase dbuf w/ global_load_lds.
template<int RELU, int OUTBF16>
__global__ __launch_bounds__(256, 2) void gemm_bt_kernel(
    const __hip_bfloat16* __restrict__ A, const __hip_bfloat16* __restrict__ Bt,
    const float* __restrict__ bias, void* __restrict__ Cv, int Mr, int N, int K)
{
  __shared__ __align__(16) char lds[32768];  // 2 x (A 8KB + B 8KB)
  const int tid = threadIdx.x;
  const int e = blockIdx.y;
  const int bx = blockIdx.x;
  const int tm = bx & 15;           // Mr/128 == 16
  const int tn = bx >> 4;
  const int w = tid >> 6;
  const int wu = __builtin_amdgcn_readfirstlane(w);
  const int l = tid & 63;
  const int wr = w >> 1, wc = w & 1;
  const int l15 = l & 15, khi = l >> 4;

  const __hip_bfloat16* Ab = A + (size_t)e * Mr * K + (size_t)tm * 128 * K;
  const __hip_bfloat16* Bb = Bt + (size_t)e * N * K + (size_t)tn * 128 * K;
  const int rowA = tid >> 2;        // + i*64
  const int seg = (tid & 3) * 8;    // element offset within 32-wide k-slice

  f32x4 acc[4][4];
  #pragma unroll
  for (int m = 0; m < 4; ++m)
    #pragma unroll
    for (int n = 0; n < 4; ++n)
      acc[m][n] = (f32x4){0.f, 0.f, 0.f, 0.f};

  auto stage = [&](int k0, int buf) {
    char* base = lds + buf * 16384;
    #pragma unroll
    for (int i = 0; i < 2; ++i) {
      int row = i * 64 + rowA;
      gll16(Ab + (size_t)row * K + k0 + seg, base + (i * 4 + wu) * 1024);
      gll16(Bb + (size_t)row * K + k0 + seg, base + 8192 + (i * 4 + wu) * 1024);
    }
  };

  const int nk = K >> 5;
  stage(0, 0);
  __syncthreads();
  int cur = 0;
  for (int t = 0; t < nk; ++t) {
    if (t + 1 < nk) stage((t + 1) << 5, cur ^ 1);
    const char* la = lds + cur * 16384 + (wr * 64 + l15) * 64 + khi * 16;
    const char* lb = lds + cur * 16384 + 8192 + (wc * 64 + l15) * 64 + khi * 16;
    short8 af[4], bf[4];
    #pragma unroll
    for (int m = 0; m < 4; ++m) af[m] = *(const short8*)(la + m * 1024);
    #pragma unroll
    for (int n = 0; n < 4; ++n) bf[n] = *(const short8*)(lb + n * 1024);
    #pragma unroll
    for (int m = 0; m < 4; ++m)
      #pragma unroll
      for (int n = 0; n < 4; ++n)
        acc[m][n] = __builtin_amdgcn_mfma_f32_16x16x32_bf16(af[m], bf[n], acc[m][n], 0, 0, 0);
    __syncthreads();
    cur ^= 1;
  }

  const float* be = bias + (size_t)e * N + tn * 128;
  const size_t cbase = ((size_t)e * Mr + (size_t)tm * 128) * N + (size_t)tn * 128;
  __hip_bfloat16* C16 = (__hip_bfloat16*)Cv + cbase;
  float* C32 = (float*)Cv + cbase;
  #pragma unroll
  for (int n = 0; n < 4; ++n) {
    int col = wc * 64 + n * 16 + l15;
    float bv = be[col];
    #pragma unroll
    for (int m = 0; m < 4; ++m) {
      int row0 = wr * 64 + m * 16 + khi * 4;
      #pragma unroll
      for (int j = 0; j < 4; ++j) {
        float v = acc[m][n][j] + bv;
        if (RELU) v = fmaxf(v, 0.f);
        if (OUTBF16) C16[(size_t)(row0 + j) * N + col] = __float2bfloat16(v);
        else         C32[(size_t)(row0 + j) * N + col] = v;
      }
    }
  }
}

// ---------------- combine: y[s] = sum_k gw * eo[flat] ----------------
__global__ __launch_bounds__(256) void combine_kernel(
    const float* __restrict__ eo, const int* __restrict__ gflat,
    const float* __restrict__ gw, float* __restrict__ y)
{
  const int s = blockIdx.x;
  const int f0 = gflat[s * 2 + 0], f1 = gflat[s * 2 + 1];
  const float g0 = gw[s * 2 + 0], g1 = gw[s * 2 + 1];
  const int c = threadIdx.x * 4;
  float4 a = *(const float4*)&eo[(size_t)f0 * MDIM + c];
  float4 b = *(const float4*)&eo[(size_t)f1 * MDIM + c];
  float4 r;
  r.x = g0 * a.x + g1 * b.x; r.y = g0 * a.y + g1 * b.y;
  r.z = g0 * a.z + g1 * b.z; r.w = g0 * a.w + g1 * b.w;
  *(float4*)&y[(size_t)s * MDIM + c] = r;
}

extern "C" void kernel_launch(void* const* d_in, const int* in_sizes, int n_in,
                              void* d_out, int out_size, void* d_ws, size_t ws_size,
                              hipStream_t stream)
{
  (void)in_sizes; (void)n_in; (void)out_size; (void)ws_size;
  const float* x  = (const float*)d_in[0];
  const float* wg = (const float*)d_in[1];
  const float* w1 = (const float*)d_in[2];
  const float* b1 = (const float*)d_in[3];
  const float* w2 = (const float*)d_in[4];
  const float* b2 = (const float*)d_in[5];
  float* y = (float*)d_out;
  float* lloss = y + (size_t)S_TOK * MDIM;

  char* ws = (char*)d_ws;
  __hip_bfloat16* w1t  = (__hip_bfloat16*)(ws);                  // 64 MB  [E][H][M]
  __hip_bfloat16* w2t  = (__hip_bfloat16*)(ws + (64ull << 20));  // 64 MB  [E][M][H]
  __hip_bfloat16* dbuf = (__hip_bfloat16*)(ws + (128ull << 20)); // 32 MB  [E*CAP][M]
  __hip_bfloat16* hbuf = (__hip_bfloat16*)(ws + (160ull << 20)); // 128 MB [E][CAP][H]
  float* eo = (float*)(ws + (288ull << 20));                     // 64 MB  [E*CAP][M]
  char* small = ws + (352ull << 20);
  float* gates_full = (float*)(small);                 // 256 KB
  int*   topk  = (int*)  (small + 262144);             // 64 KB
  float* gnorm = (float*)(small + 262144 + 65536);     // 64 KB
  int*   gflat = (int*)  (small + 262144 + 2 * 65536); // 64 KB
  float* gwv   = (float*)(small + 262144 + 3 * 65536); // 64 KB
  int*   s2t   = (int*)  (small + 262144 + 4 * 65536); // 64 KB

  transpose_cvt_kernel<<<dim3(HDIM / 64, MDIM / 64, NEXP), 256, 0, stream>>>(w1, w1t, MDIM, HDIM);
  transpose_cvt_kernel<<<dim3(MDIM / 64, HDIM / 64, NEXP), 256, 0, stream>>>(w2, w2t, HDIM, MDIM);
  gate_kernel<<<S_TOK / 4, 256, 0, stream>>>(x, wg, gates_full, topk, gnorm);
  scan_kernel<<<1, 1024, 0, stream>>>(topk, gnorm, gates_full, gflat, gwv, s2t, lloss);
  dispatch_kernel<<<NEXP * CAP, 256, 0, stream>>>(x, s2t, dbuf);
  gemm_bt_kernel<1, 1><<<dim3(16 * (HDIM / 128), NEXP), 256, 0, stream>>>(
      dbuf, w1t, b1, (void*)hbuf, CAP, HDIM, MDIM);
  gemm_bt_kernel<0, 0><<<dim3(16 * (MDIM / 128), NEXP), 256, 0, stream>>>(
      hbuf, w2t, b2, (void*)eo, CAP, MDIM, HDIM);
  combine_kernel<<<S_TOK, 256, 0, stream>>>(eo, gflat, gwv, y);
}

// Round 2
// 409.677 us; speedup vs baseline: 1.2489x; 1.2489x over previous
//
#include <hip/hip_runtime.h>
#include <hip/hip_bf16.h>

typedef __attribute__((ext_vector_type(8))) short short8;
typedef __attribute__((ext_vector_type(8))) unsigned short u16x8;
typedef __attribute__((ext_vector_type(4))) float f32x4;
typedef unsigned int u32;

#define S_TOK 8192
#define MDIM  1024
#define NEXP  8
#define HDIM  4096
#define CAP   2048   // TOP_K * ceil(S/E) * CF = 2*1024

__device__ __forceinline__ void gll16(const void* g, void* l) {
  __builtin_amdgcn_global_load_lds((const __attribute__((address_space(1))) u32*)g,
                                   (__attribute__((address_space(3))) u32*)l, 16, 0, 0);
}

// ---------------- gate: logits, softmax, top-2, normalized gates ----------------
__global__ __launch_bounds__(256) void gate_kernel(
    const float* __restrict__ x, const float* __restrict__ wg,
    float* __restrict__ gates_full, int* __restrict__ topk, float* __restrict__ gnorm)
{
  __shared__ __align__(16) float swg[NEXP * MDIM];
  const int tid = threadIdx.x;
  #pragma unroll
  for (int i = 0; i < 8; ++i) {
    int idx = tid + i * 256;   // 2048 float4 = 8192 floats
    ((float4*)swg)[idx] = ((const float4*)wg)[idx];
  }
  __syncthreads();
  const int w = tid >> 6, l = tid & 63;
  const int s = blockIdx.x * 4 + w;
  const float* xr = x + (size_t)s * MDIM;
  float a[8] = {0,0,0,0,0,0,0,0};
  for (int j = 0; j < 16; ++j) {
    float xv = xr[l + j * 64];
    #pragma unroll
    for (int e = 0; e < 8; ++e) a[e] += xv * swg[e * MDIM + l + j * 64];
  }
  #pragma unroll
  for (int e = 0; e < 8; ++e)
    #pragma unroll
    for (int off = 32; off > 0; off >>= 1)
      a[e] += __shfl_xor(a[e], off);
  if (l == 0) {
    float m = a[0]; int i1 = 0;
    #pragma unroll
    for (int e = 1; e < 8; ++e) if (a[e] > m) { m = a[e]; i1 = e; }
    float den = 0.f, g[8];
    #pragma unroll
    for (int e = 0; e < 8; ++e) { g[e] = __expf(a[e] - m); den += g[e]; }
    float inv = 1.f / den;
    float m2 = -3.4e38f; int i2 = 0;
    #pragma unroll
    for (int e = 0; e < 8; ++e) if (e != i1 && a[e] > m2) { m2 = a[e]; i2 = e; }
    #pragma unroll
    for (int e = 0; e < 8; ++e) gates_full[(size_t)s * 8 + e] = g[e] * inv;
    float gs1 = inv;                    // exp(0)/den  (top-1 gate)
    float gs2 = __expf(m2 - m) * inv;   // top-2 gate
    float ssum = fmaxf(gs1 + gs2, 1.1920929e-7f);
    topk[s * 2 + 0] = i1; topk[s * 2 + 1] = i2;
    gnorm[s * 2 + 0] = gs1 / ssum; gnorm[s * 2 + 1] = gs2 / ssum;
  }
}

// ---------------- scan: token-order locations, capacity, slot map, l_loss ----------------
__global__ __launch_bounds__(1024) void scan_kernel(
    const int* __restrict__ topk, const float* __restrict__ gnorm,
    const float* __restrict__ gates_full,
    int* __restrict__ gflat, float* __restrict__ gw,
    int* __restrict__ slot2tok, float* __restrict__ lloss)
{
  __shared__ union {
    float mef[8192];
    struct { u16x8 s0[1024]; u16x8 s1[1024]; } sc;
  } sh;
  __shared__ float me_s[8];
  __shared__ int tot_s[8];
  const int t = threadIdx.x;

  #pragma unroll
  for (int i = 0; i < 16; ++i) slot2tok[t + i * 1024] = -1;

  int e1[8], e2[8];
  #pragma unroll
  for (int i = 0; i < 8; ++i) {
    e1[i] = topk[(t * 8 + i) * 2 + 0];
    e2[i] = topk[(t * 8 + i) * 2 + 1];
  }

  // ---- me = sum of full gates per expert ----
  float ms[8] = {0,0,0,0,0,0,0,0};
  for (int i = 0; i < 8; ++i) {
    #pragma unroll
    for (int e = 0; e < 8; ++e) ms[e] += gates_full[(size_t)(t * 8 + i) * 8 + e];
  }
  #pragma unroll
  for (int e = 0; e < 8; ++e) sh.mef[t * 8 + e] = ms[e];
  __syncthreads();
  for (int off = 512; off > 0; off >>= 1) {
    if (t < off) {
      #pragma unroll
      for (int e = 0; e < 8; ++e) sh.mef[t * 8 + e] += sh.mef[(t + off) * 8 + e];
    }
    __syncthreads();
  }
  if (t < 8) me_s[t] = sh.mef[t];
  __syncthreads();

  // ---- per-thread local counts (8 tokens, packed 4-bit) ----
  u32 p0 = 0, p1 = 0;
  #pragma unroll
  for (int i = 0; i < 8; ++i) { p0 += 1u << (4 * e1[i]); p1 += 1u << (4 * e2[i]); }
  union { unsigned short a[8]; u16x8 v; } c0u, c1u;
  #pragma unroll
  for (int e = 0; e < 8; ++e) {
    c0u.a[e] = (unsigned short)((p0 >> (4 * e)) & 15u);
    c1u.a[e] = (unsigned short)((p1 >> (4 * e)) & 15u);
  }
  sh.sc.s0[t] = c0u.v;
  sh.sc.s1[t] = c1u.v;
  __syncthreads();
  // inclusive Hillis-Steele scan over 1024 threads (8-wide vectors)
  for (int off = 1; off < 1024; off <<= 1) {
    u16x8 v0 = (u16x8)(unsigned short)0, v1 = v0;
    const bool p = (t >= off);
    if (p) { v0 = sh.sc.s0[t - off]; v1 = sh.sc.s1[t - off]; }
    __syncthreads();
    if (p) { sh.sc.s0[t] = sh.sc.s0[t] + v0; sh.sc.s1[t] = sh.sc.s1[t] + v1; }
    __syncthreads();
  }
  if (t == 0) {
    u16x8 tv = sh.sc.s0[1023];
    #pragma unroll
    for (int e = 0; e < 8; ++e) tot_s[e] = (int)tv[e];
  }
  __syncthreads();
  // exclusive (own row only; no cross-thread reads after this)
  sh.sc.s0[t] = sh.sc.s0[t] - c0u.v;
  sh.sc.s1[t] = sh.sc.s1[t] - c1u.v;

  const unsigned short* r0 = (const unsigned short*)&sh.sc.s0[t];
  const unsigned short* r1 = (const unsigned short*)&sh.sc.s1[t];
  #pragma unroll
  for (int i = 0; i < 8; ++i) {
    int s = t * 8 + i;
    int cnt0 = 0, cnt1 = 0;
    #pragma unroll
    for (int j = 0; j < 8; ++j) if (j < i) { cnt0 += (e1[j] == e1[i]); cnt1 += (e2[j] == e2[i]); }
    int loc0 = (int)r0[e1[i]] + cnt0;
    int loc1 = tot_s[e2[i]] + (int)r1[e2[i]] + cnt1;
    int v0 = loc0 < CAP, v1 = loc1 < CAP;
    int f0 = e1[i] * CAP + (loc0 < CAP ? loc0 : CAP - 1);
    int f1 = e2[i] * CAP + (loc1 < CAP ? loc1 : CAP - 1);
    gflat[s * 2 + 0] = f0; gflat[s * 2 + 1] = f1;
    float gn0 = gnorm[s * 2 + 0], gn1 = gnorm[s * 2 + 1];
    gw[s * 2 + 0] = v0 ? gn0 : 0.f;
    gw[s * 2 + 1] = v1 ? gn1 : 0.f;
    if (v0) slot2tok[f0] = s;
    if (v1) slot2tok[f1] = s;
  }
  if (t == 0) {
    float ll = 0.f;
    #pragma unroll
    for (int e = 0; e < 8; ++e) ll += me_s[e] * (float)tot_s[e];
    *lloss = ll * ((float)NEXP / ((float)S_TOK * (float)S_TOK));
  }
}

// ---------------- transpose + f32->bf16: in [R][C] -> out [C][R] ----------------
__global__ __launch_bounds__(256) void transpose_cvt_kernel(
    const float* __restrict__ in, __hip_bfloat16* __restrict__ out, int R, int C)
{
  __shared__ float tile[64][68];
  const float* ine = in + (size_t)blockIdx.z * R * C;
  __hip_bfloat16* oute = out + (size_t)blockIdx.z * R * C;
  const int cb = blockIdx.x * 64;
  const int rb = blockIdx.y * 64;
  const int t = threadIdx.x;
  const int rr = t >> 4;
  const int c4 = (t & 15) * 4;
  #pragma unroll
  for (int i = 0; i < 4; ++i) {
    int r = rr + i * 16;
    float4 v = *(const float4*)&ine[(size_t)(rb + r) * C + cb + c4];
    tile[r][c4 + 0] = v.x; tile[r][c4 + 1] = v.y;
    tile[r][c4 + 2] = v.z; tile[r][c4 + 3] = v.w;
  }
  __syncthreads();
  const int oc = t >> 2;
  const int sg = (t & 3) * 16;
  union { unsigned short u[16]; ushort4 v4[4]; } tu;
  #pragma unroll
  for (int j = 0; j < 16; ++j) {
    __hip_bfloat16 b = __float2bfloat16(tile[sg + j][oc]);
    tu.u[j] = *reinterpret_cast<const unsigned short*>(&b);
  }
  ushort4* dst = (ushort4*)&oute[(size_t)(cb + oc) * R + rb + sg];
  #pragma unroll
  for (int q = 0; q < 4; ++q) dst[q] = tu.v4[q];
}

// ---------------- dispatch: gather x rows (f32->bf16) into [E*CAP][M] ----------------
__global__ __launch_bounds__(256) void dispatch_kernel(
    const float* __restrict__ x, const int* __restrict__ slot2tok,
    __hip_bfloat16* __restrict__ dmat)
{
  const int slot = blockIdx.x;
  const int tok = slot2tok[slot];
  const int c = threadIdx.x * 4;
  float4 v = {0.f, 0.f, 0.f, 0.f};
  if (tok >= 0) v = *(const float4*)&x[(size_t)tok * MDIM + c];
  union { unsigned short u[4]; ushort4 v4; } o;
  __hip_bfloat16 b0 = __float2bfloat16(v.x); o.u[0] = *(unsigned short*)&b0;
  __hip_bfloat16 b1 = __float2bfloat16(v.y); o.u[1] = *(unsigned short*)&b1;
  __hip_bfloat16 b2 = __float2bfloat16(v.z); o.u[2] = *(unsigned short*)&b2;
  __hip_bfloat16 b3 = __float2bfloat16(v.w); o.u[3] = *(unsigned short*)&b3;
  *(ushort4*)&dmat[(size_t)slot * MDIM + c] = o.v4;
}

// ---------------- grouped GEMM, 256x256 tile, BK=64, 8-phase counted-vmcnt ----------------
// A: [E][Mr][K] bf16 row-major; Bt: [E][N][K] bf16 (K-contiguous).
// 512 threads = 8 waves (2M x 4N); per-wave out 128x64 (interleaved halves).
// LDS 128KB: 2 dbuf x (A 2x16KB halves + B 2x16KB halves); half = 128 rows x 64 bf16.
// Swizzle: 16B-slot' = slot ^ (row&7); staged via inverse-swizzled global source (linear LDS dest).
template<int RELU, int OUTBF16>
__global__ __launch_bounds__(512, 2) void gemm256_kernel(
    const __hip_bfloat16* __restrict__ A, const __hip_bfloat16* __restrict__ Bt,
    const float* __restrict__ bias, void* __restrict__ Cv,
    int Mr, int N, int K, int TN, int tiles_per_e, int nwg)
{
  __shared__ __align__(16) char lds[131072];
  const int tid = threadIdx.x;
  // XCD-aware bijective swizzle (nwg % 8 == 0 guaranteed by launch)
  const int bid = blockIdx.x;
  const int cpx = nwg >> 3;
  const int swz = (bid & 7) * cpx + (bid >> 3);
  const int e  = swz / tiles_per_e;
  const int rem = swz - e * tiles_per_e;
  const int tm = rem / TN;
  const int tn = rem - tm * TN;

  const int w  = tid >> 6, l = tid & 63;
  const int wr = w >> 2;          // 0..1  (M warps)
  const int wc = w & 3;           // 0..3  (N warps)
  const int l15 = l & 15, khi = l >> 4;
  const int rx = l15 & 7;         // read-side swizzle key
  const int wu = __builtin_amdgcn_readfirstlane(w);

  const __hip_bfloat16* Abase = A  + ((size_t)e * Mr + (size_t)tm * 256) * K;
  const __hip_bfloat16* Bbase = Bt + ((size_t)e * N  + (size_t)tn * 256) * K;

  // staging map: thread tid covers rows {srow, srow+64} of a half, 16B at global slot gs
  const int srow = tid >> 3;                       // 0..63
  const int gs   = (tid & 7) ^ (srow & 7);         // inverse-swizzled source slot

  auto stage = [&](const __hip_bfloat16* base, int h, int isB, int k0, int buf) {
    char* dst = lds + buf * 65536 + isB * 32768 + h * 16384 + wu * 1024;
    const __hip_bfloat16* src = base + (size_t)(h * 128 + srow) * K + k0 + gs * 8;
    gll16(src, dst);
    gll16(src + (size_t)64 * K, dst + 8192);
  };

  f32x4 acc[8][4];
  #pragma unroll
  for (int m = 0; m < 8; ++m)
    #pragma unroll
    for (int n = 0; n < 4; ++n)
      acc[m][n] = (f32x4){0.f, 0.f, 0.f, 0.f};

  short8 af[4][2];   // current A-half fragments (4 m x 2 kk)
  short8 bfr[4][2];  // both B halves resident (4 n x 2 kk)

  auto loadA = [&](int qm, int buf) {
    const char* p = lds + buf * 65536 + qm * 16384 + (wr * 64 + l15) * 128;
    #pragma unroll
    for (int mi = 0; mi < 4; ++mi)
      #pragma unroll
      for (int kk = 0; kk < 2; ++kk)
        af[mi][kk] = *(const short8*)(p + mi * 2048 + ((((kk << 2) | khi) ^ rx) << 4));
  };
  auto loadB = [&](int qn, int buf) {
    const char* p = lds + buf * 65536 + 32768 + qn * 16384 + (wc * 32 + l15) * 128;
    #pragma unroll
    for (int ni = 0; ni < 2; ++ni)
      #pragma unroll
      for (int kk = 0; kk < 2; ++kk)
        bfr[qn * 2 + ni][kk] = *(const short8*)(p + ni * 2048 + ((((kk << 2) | khi) ^ rx) << 4));
  };
  auto mfma8 = [&](int qm, int qn) {
    #pragma unroll
    for (int mi = 0; mi < 4; ++mi)
      #pragma unroll
      for (int ni = 0; ni < 2; ++ni)
        #pragma unroll
        for (int kk = 0; kk < 2; ++kk)
          acc[qm * 4 + mi][qn * 2 + ni] = __builtin_amdgcn_mfma_f32_16x16x32_bf16(
              af[mi][kk], bfr[qn * 2 + ni][kk], acc[qm * 4 + mi][qn * 2 + ni], 0, 0, 0);
  };

  #define BAR() __builtin_amdgcn_s_barrier()
  #define W4() asm volatile("s_waitcnt vmcnt(4)" ::: "memory")
  #define W2() asm volatile("s_waitcnt vmcnt(2)" ::: "memory")
  #define W0() asm volatile("s_waitcnt vmcnt(0)" ::: "memory")

  // prologue: tile 0 halves in order A0,B0,B1,A1
  stage(Abase, 0, 0, 0, 0);
  stage(Bbase, 0, 1, 0, 0);
  stage(Bbase, 1, 1, 0, 0);
  stage(Abase, 1, 0, 0, 0);
  W4(); BAR();   // A0,B0 of t0 resident (all waves)

  const int NT = K >> 6;
  for (int t = 0; t < NT; ++t) {
    const int buf = t & 1, nbuf = buf ^ 1;
    const bool st = (t + 1 < NT);
    const int k0n = (t + 1) << 6;
    // ---- phase 1: quadrant (A0,B0) ----
    loadA(0, buf); loadB(0, buf);
    if (st) stage(Abase, 0, 0, k0n, nbuf);
    BAR();
    __builtin_amdgcn_s_setprio(1); mfma8(0, 0); __builtin_amdgcn_s_setprio(0);
    if (st) { W4(); } else { W2(); }   // ensure B1(t)
    BAR();
    // ---- phase 2: quadrant (A0,B1) ----
    loadB(1, buf);
    if (st) stage(Bbase, 0, 1, k0n, nbuf);
    BAR();
    __builtin_amdgcn_s_setprio(1); mfma8(0, 1); __builtin_amdgcn_s_setprio(0);
    if (st) { W4(); } else { W0(); }   // ensure A1(t)
    BAR();
    // ---- phase 3: quadrant (A1,B0) ----
    loadA(1, buf);
    if (st) stage(Bbase, 1, 1, k0n, nbuf);
    BAR();
    __builtin_amdgcn_s_setprio(1); mfma8(1, 0); __builtin_amdgcn_s_setprio(0);
    BAR();
    // ---- phase 4: quadrant (A1,B1) ----
    if (st) stage(Abase, 1, 0, k0n, nbuf);
    BAR();
    __builtin_amdgcn_s_setprio(1); mfma8(1, 1); __builtin_amdgcn_s_setprio(0);
    if (st) { W4(); }                  // ensure A0,B0 of t+1
    BAR();
  }
  #undef BAR
  #undef W4
  #undef W2
  #undef W0

  // ---- epilogue: bias (+ReLU) and store ----
  const float* be = bias + (size_t)e * N + (size_t)tn * 256;
  const size_t cbase = ((size_t)e * Mr + (size_t)tm * 256) * N + (size_t)tn * 256;
  __hip_bfloat16* C16 = (__hip_bfloat16*)Cv + cbase;
  float* C32 = (float*)Cv + cbase;
  #pragma unroll
  for (int n = 0; n < 4; ++n) {
    const int colL = (n >> 1) * 128 + wc * 32 + (n & 1) * 16 + l15;
    const float bv = be[colL];
    #pragma unroll
    for (int m = 0; m < 8; ++m) {
      const int rowL = (m >> 2) * 128 + wr * 64 + (m & 3) * 16 + khi * 4;
      #pragma unroll
      for (int j = 0; j < 4; ++j) {
        float v = acc[m][n][j] + bv;
        if (RELU) v = fmaxf(v, 0.f);
        if (OUTBF16) C16[(size_t)(rowL + j) * N + colL] = __float2bfloat16(v);
        else         C32[(size_t)(rowL + j) * N + colL] = v;
      }
    }
  }
}

// ---------------- combine: y[s] = sum_k gw * eo[flat] ----------------
__global__ __launch_bounds__(256) void combine_kernel(
    const float* __restrict__ eo, const int* __restrict__ gflat,
    const float* __restrict__ gw, float* __restrict__ y)
{
  const int s = blockIdx.x;
  const int f0 = gflat[s * 2 + 0], f1 = gflat[s * 2 + 1];
  const float g0 = gw[s * 2 + 0], g1 = gw[s * 2 + 1];
  const int c = threadIdx.x * 4;
  float4 a = *(const float4*)&eo[(size_t)f0 * MDIM + c];
  float4 b = *(const float4*)&eo[(size_t)f1 * MDIM + c];
  float4 r;
  r.x = g0 * a.x + g1 * b.x; r.y = g0 * a.y + g1 * b.y;
  r.z = g0 * a.z + g1 * b.z; r.w = g0 * a.w + g1 * b.w;
  *(float4*)&y[(size_t)s * MDIM + c] = r;
}

extern "C" void kernel_launch(void* const* d_in, const int* in_sizes, int n_in,
                              void* d_out, int out_size, void* d_ws, size_t ws_size,
                              hipStream_t stream)
{
  (void)in_sizes; (void)n_in; (void)out_size; (void)ws_size;
  const float* x  = (const float*)d_in[0];
  const float* wg = (const float*)d_in[1];
  const float* w1 = (const float*)d_in[2];
  const float* b1 = (const float*)d_in[3];
  const float* w2 = (const float*)d_in[4];
  const float* b2 = (const float*)d_in[5];
  float* y = (float*)d_out;
  float* lloss = y + (size_t)S_TOK * MDIM;

  char* ws = (char*)d_ws;
  __hip_bfloat16* w1t  = (__hip_bfloat16*)(ws);                  // 64 MB  [E][H][M]
  __hip_bfloat16* w2t  = (__hip_bfloat16*)(ws + (64ull << 20));  // 64 MB  [E][M][H]
  __hip_bfloat16* dbuf = (__hip_bfloat16*)(ws + (128ull << 20)); // 32 MB  [E*CAP][M]
  __hip_bfloat16* hbuf = (__hip_bfloat16*)(ws + (160ull << 20)); // 128 MB [E][CAP][H]
  float* eo = (float*)(ws + (288ull << 20));                     // 64 MB  [E*CAP][M]
  char* small = ws + (352ull << 20);
  float* gates_full = (float*)(small);                 // 256 KB
  int*   topk  = (int*)  (small + 262144);             // 64 KB
  float* gnorm = (float*)(small + 262144 + 65536);     // 64 KB
  int*   gflat = (int*)  (small + 262144 + 2 * 65536); // 64 KB
  float* gwv   = (float*)(small + 262144 + 3 * 65536); // 64 KB
  int*   s2t   = (int*)  (small + 262144 + 4 * 65536); // 64 KB

  transpose_cvt_kernel<<<dim3(HDIM / 64, MDIM / 64, NEXP), 256, 0, stream>>>(w1, w1t, MDIM, HDIM);
  transpose_cvt_kernel<<<dim3(MDIM / 64, HDIM / 64, NEXP), 256, 0, stream>>>(w2, w2t, HDIM, MDIM);
  gate_kernel<<<S_TOK / 4, 256, 0, stream>>>(x, wg, gates_full, topk, gnorm);
  scan_kernel<<<1, 1024, 0, stream>>>(topk, gnorm, gates_full, gflat, gwv, s2t, lloss);
  dispatch_kernel<<<NEXP * CAP, 256, 0, stream>>>(x, s2t, dbuf);
  // GEMM1: per expert M=2048, N=4096, K=1024 -> 8x16 tiles x 8 experts = 1024 wg
  gemm256_kernel<1, 1><<<1024, 512, 0, stream>>>(
      dbuf, w1t, b1, (void*)hbuf, CAP, HDIM, MDIM, 16, 128, 1024);
  // GEMM2: per expert M=2048, N=1024, K=4096 -> 8x4 tiles x 8 experts = 256 wg
  gemm256_kernel<0, 0><<<256, 512, 0, stream>>>(
      hbuf, w2t, b2, (void*)eo, CAP, MDIM, HDIM, 4, 32, 256);
  combine_kernel<<<S_TOK, 256, 0, stream>>>(eo, gflat, gwv, y);
}

// Round 4
// 389.726 us; speedup vs baseline: 1.3129x; 1.0512x over previous
//
#include <hip/hip_runtime.h>
#include <hip/hip_bf16.h>

typedef __attribute__((ext_vector_type(8))) short short8;
typedef __attribute__((ext_vector_type(8))) unsigned short u16x8;
typedef __attribute__((ext_vector_type(4))) float f32x4;
typedef unsigned int u32;

#define S_TOK 8192
#define MDIM  1024
#define NEXP  8
#define HDIM  4096
#define CAP   2048   // TOP_K * ceil(S/E) * CF = 2*1024

__device__ __forceinline__ void gll16(const void* g, void* l) {
  __builtin_amdgcn_global_load_lds((const __attribute__((address_space(1))) u32*)g,
                                   (__attribute__((address_space(3))) u32*)l, 16, 0, 0);
}

// ---------------- gate: logits, softmax, top-2, normalized gates ----------------
__global__ __launch_bounds__(256) void gate_kernel(
    const float* __restrict__ x, const float* __restrict__ wg,
    float* __restrict__ gates_full, int* __restrict__ topk, float* __restrict__ gnorm)
{
  __shared__ __align__(16) float swg[NEXP * MDIM];
  const int tid = threadIdx.x;
  #pragma unroll
  for (int i = 0; i < 8; ++i) {
    int idx = tid + i * 256;   // 2048 float4 = 8192 floats
    ((float4*)swg)[idx] = ((const float4*)wg)[idx];
  }
  __syncthreads();
  const int w = tid >> 6, l = tid & 63;
  const int s = blockIdx.x * 4 + w;
  const float* xr = x + (size_t)s * MDIM;
  float a[8] = {0,0,0,0,0,0,0,0};
  for (int j = 0; j < 16; ++j) {
    float xv = xr[l + j * 64];
    #pragma unroll
    for (int e = 0; e < 8; ++e) a[e] += xv * swg[e * MDIM + l + j * 64];
  }
  #pragma unroll
  for (int e = 0; e < 8; ++e)
    #pragma unroll
    for (int off = 32; off > 0; off >>= 1)
      a[e] += __shfl_xor(a[e], off);
  if (l == 0) {
    float m = a[0]; int i1 = 0;
    #pragma unroll
    for (int e = 1; e < 8; ++e) if (a[e] > m) { m = a[e]; i1 = e; }
    float den = 0.f, g[8];
    #pragma unroll
    for (int e = 0; e < 8; ++e) { g[e] = __expf(a[e] - m); den += g[e]; }
    float inv = 1.f / den;
    float m2 = -3.4e38f; int i2 = 0;
    #pragma unroll
    for (int e = 0; e < 8; ++e) if (e != i1 && a[e] > m2) { m2 = a[e]; i2 = e; }
    #pragma unroll
    for (int e = 0; e < 8; ++e) gates_full[(size_t)s * 8 + e] = g[e] * inv;
    float gs1 = inv;                    // exp(0)/den  (top-1 gate)
    float gs2 = __expf(m2 - m) * inv;   // top-2 gate
    float ssum = fmaxf(gs1 + gs2, 1.1920929e-7f);
    topk[s * 2 + 0] = i1; topk[s * 2 + 1] = i2;
    gnorm[s * 2 + 0] = gs1 / ssum; gnorm[s * 2 + 1] = gs2 / ssum;
  }
}

// ---------------- scan: token-order locations, capacity, slot map, l_loss ----------------
__global__ __launch_bounds__(1024) void scan_kernel(
    const int* __restrict__ topk, const float* __restrict__ gnorm,
    const float* __restrict__ gates_full,
    int* __restrict__ gflat, float* __restrict__ gw,
    int* __restrict__ slot2tok, float* __restrict__ lloss)
{
  __shared__ union {
    float mef[8192];
    struct { u16x8 s0[1024]; u16x8 s1[1024]; } sc;
  } sh;
  __shared__ float me_s[8];
  __shared__ int tot_s[8];
  const int t = threadIdx.x;

  #pragma unroll
  for (int i = 0; i < 16; ++i) slot2tok[t + i * 1024] = -1;

  int e1[8], e2[8];
  #pragma unroll
  for (int i = 0; i < 8; ++i) {
    e1[i] = topk[(t * 8 + i) * 2 + 0];
    e2[i] = topk[(t * 8 + i) * 2 + 1];
  }

  // ---- me = sum of full gates per expert ----
  float ms[8] = {0,0,0,0,0,0,0,0};
  for (int i = 0; i < 8; ++i) {
    #pragma unroll
    for (int e = 0; e < 8; ++e) ms[e] += gates_full[(size_t)(t * 8 + i) * 8 + e];
  }
  #pragma unroll
  for (int e = 0; e < 8; ++e) sh.mef[t * 8 + e] = ms[e];
  __syncthreads();
  for (int off = 512; off > 0; off >>= 1) {
    if (t < off) {
      #pragma unroll
      for (int e = 0; e < 8; ++e) sh.mef[t * 8 + e] += sh.mef[(t + off) * 8 + e];
    }
    __syncthreads();
  }
  if (t < 8) me_s[t] = sh.mef[t];
  __syncthreads();

  // ---- per-thread local counts (8 tokens, packed 4-bit) ----
  u32 p0 = 0, p1 = 0;
  #pragma unroll
  for (int i = 0; i < 8; ++i) { p0 += 1u << (4 * e1[i]); p1 += 1u << (4 * e2[i]); }
  union { unsigned short a[8]; u16x8 v; } c0u, c1u;
  #pragma unroll
  for (int e = 0; e < 8; ++e) {
    c0u.a[e] = (unsigned short)((p0 >> (4 * e)) & 15u);
    c1u.a[e] = (unsigned short)((p1 >> (4 * e)) & 15u);
  }
  sh.sc.s0[t] = c0u.v;
  sh.sc.s1[t] = c1u.v;
  __syncthreads();
  // inclusive Hillis-Steele scan over 1024 threads (8-wide vectors)
  for (int off = 1; off < 1024; off <<= 1) {
    u16x8 v0 = (u16x8)(unsigned short)0, v1 = v0;
    const bool p = (t >= off);
    if (p) { v0 = sh.sc.s0[t - off]; v1 = sh.sc.s1[t - off]; }
    __syncthreads();
    if (p) { sh.sc.s0[t] = sh.sc.s0[t] + v0; sh.sc.s1[t] = sh.sc.s1[t] + v1; }
    __syncthreads();
  }
  if (t == 0) {
    u16x8 tv = sh.sc.s0[1023];
    #pragma unroll
    for (int e = 0; e < 8; ++e) tot_s[e] = (int)tv[e];
  }
  __syncthreads();
  // exclusive (own row only; no cross-thread reads after this)
  sh.sc.s0[t] = sh.sc.s0[t] - c0u.v;
  sh.sc.s1[t] = sh.sc.s1[t] - c1u.v;

  const unsigned short* r0 = (const unsigned short*)&sh.sc.s0[t];
  const unsigned short* r1 = (const unsigned short*)&sh.sc.s1[t];
  #pragma unroll
  for (int i = 0; i < 8; ++i) {
    int s = t * 8 + i;
    int cnt0 = 0, cnt1 = 0;
    #pragma unroll
    for (int j = 0; j < 8; ++j) if (j < i) { cnt0 += (e1[j] == e1[i]); cnt1 += (e2[j] == e2[i]); }
    int loc0 = (int)r0[e1[i]] + cnt0;
    int loc1 = tot_s[e2[i]] + (int)r1[e2[i]] + cnt1;
    int v0 = loc0 < CAP, v1 = loc1 < CAP;
    int f0 = e1[i] * CAP + (loc0 < CAP ? loc0 : CAP - 1);
    int f1 = e2[i] * CAP + (loc1 < CAP ? loc1 : CAP - 1);
    gflat[s * 2 + 0] = f0; gflat[s * 2 + 1] = f1;
    float gn0 = gnorm[s * 2 + 0], gn1 = gnorm[s * 2 + 1];
    gw[s * 2 + 0] = v0 ? gn0 : 0.f;
    gw[s * 2 + 1] = v1 ? gn1 : 0.f;
    if (v0) slot2tok[f0] = s;
    if (v1) slot2tok[f1] = s;
  }
  if (t == 0) {
    float ll = 0.f;
    #pragma unroll
    for (int e = 0; e < 8; ++e) ll += me_s[e] * (float)tot_s[e];
    *lloss = ll * ((float)NEXP / ((float)S_TOK * (float)S_TOK));
  }
}

// ---------------- transpose + f32->bf16: in [R][C] -> out [C][R] ----------------
__global__ __launch_bounds__(256) void transpose_cvt_kernel(
    const float* __restrict__ in, __hip_bfloat16* __restrict__ out, int R, int C)
{
  __shared__ float tile[64][68];
  const float* ine = in + (size_t)blockIdx.z * R * C;
  __hip_bfloat16* oute = out + (size_t)blockIdx.z * R * C;
  const int cb = blockIdx.x * 64;
  const int rb = blockIdx.y * 64;
  const int t = threadIdx.x;
  const int rr = t >> 4;
  const int c4 = (t & 15) * 4;
  #pragma unroll
  for (int i = 0; i < 4; ++i) {
    int r = rr + i * 16;
    float4 v = *(const float4*)&ine[(size_t)(rb + r) * C + cb + c4];
    tile[r][c4 + 0] = v.x; tile[r][c4 + 1] = v.y;
    tile[r][c4 + 2] = v.z; tile[r][c4 + 3] = v.w;
  }
  __syncthreads();
  const int oc = t >> 2;
  const int sg = (t & 3) * 16;
  union { unsigned short u[16]; ushort4 v4[4]; } tu;
  #pragma unroll
  for (int j = 0; j < 16; ++j) {
    __hip_bfloat16 b = __float2bfloat16(tile[sg + j][oc]);
    tu.u[j] = *reinterpret_cast<const unsigned short*>(&b);
  }
  ushort4* dst = (ushort4*)&oute[(size_t)(cb + oc) * R + rb + sg];
  #pragma unroll
  for (int q = 0; q < 4; ++q) dst[q] = tu.v4[q];
}

// ---------------- dispatch: gather x rows (f32->bf16) into [E*CAP][M] ----------------
__global__ __launch_bounds__(256) void dispatch_kernel(
    const float* __restrict__ x, const int* __restrict__ slot2tok,
    __hip_bfloat16* __restrict__ dmat)
{
  const int slot = blockIdx.x;
  const int tok = slot2tok[slot];
  const int c = threadIdx.x * 4;
  float4 v = {0.f, 0.f, 0.f, 0.f};
  if (tok >= 0) v = *(const float4*)&x[(size_t)tok * MDIM + c];
  union { unsigned short u[4]; ushort4 v4; } o;
  __hip_bfloat16 b0 = __float2bfloat16(v.x); o.u[0] = *(unsigned short*)&b0;
  __hip_bfloat16 b1 = __float2bfloat16(v.y); o.u[1] = *(unsigned short*)&b1;
  __hip_bfloat16 b2 = __float2bfloat16(v.z); o.u[2] = *(unsigned short*)&b2;
  __hip_bfloat16 b3 = __float2bfloat16(v.w); o.u[3] = *(unsigned short*)&b3;
  *(ushort4*)&dmat[(size_t)slot * MDIM + c] = o.v4;
}

// ---------------- grouped GEMM, 256x256 tile, BK=64, 2-long-phase counted-vmcnt ----------------
// A: [E][Mr][K] bf16 row-major; Bt: [E][N][K] bf16 (K-contiguous).
// 512 threads = 8 waves (2M x 4N); per-wave out 128x64 (interleaved halves).
// LDS 128KB: 2 dbuf x (A 2x16KB halves + B 2x16KB halves); half = 128 rows x 64 bf16.
// Swizzle: 16B-slot' = slot ^ (row&7); staged via inverse-swizzled global source (linear LDS dest).
// Per K-tile: phase A = A0x{B0,B1} (32 MFMA), stage A0',B0',B1', W6, BAR;
//             phase B = A1x{B0,B1} (32 MFMA), stage A1',           W2, BAR.
template<int RELU, int OUTBF16>
__global__ __launch_bounds__(512, 2) void gemm256_kernel(
    const __hip_bfloat16* __restrict__ A, const __hip_bfloat16* __restrict__ Bt,
    const float* __restrict__ bias, void* __restrict__ Cv,
    int Mr, int N, int K, int TN, int tiles_per_e, int nwg)
{
  __shared__ __align__(16) char lds[131072];
  const int tid = threadIdx.x;
  // XCD-aware bijective swizzle (nwg % 8 == 0 guaranteed by launch)
  const int bid = blockIdx.x;
  const int cpx = nwg >> 3;
  const int swz = (bid & 7) * cpx + (bid >> 3);
  const int e  = swz / tiles_per_e;
  const int rem = swz - e * tiles_per_e;
  const int tm = rem / TN;
  const int tn = rem - tm * TN;

  const int w  = tid >> 6, l = tid & 63;
  const int wr = w >> 2;          // 0..1  (M warps)
  const int wc = w & 3;           // 0..3  (N warps)
  const int l15 = l & 15, khi = l >> 4;
  const int rx = l15 & 7;         // read-side swizzle key
  const int wu = __builtin_amdgcn_readfirstlane(w);

  const __hip_bfloat16* Abase = A  + ((size_t)e * Mr + (size_t)tm * 256) * K;
  const __hip_bfloat16* Bbase = Bt + ((size_t)e * N  + (size_t)tn * 256) * K;

  // staging map: thread tid covers rows {srow, srow+64} of a half, 16B at global slot gs
  const int srow = tid >> 3;                       // 0..63
  const int gs   = (tid & 7) ^ (srow & 7);         // inverse-swizzled source slot

  auto stage = [&](const __hip_bfloat16* base, int h, int isB, int k0, int buf) {
    char* dst = lds + buf * 65536 + isB * 32768 + h * 16384 + wu * 1024;
    const __hip_bfloat16* src = base + (size_t)(h * 128 + srow) * K + k0 + gs * 8;
    gll16(src, dst);
    gll16(src + (size_t)64 * K, dst + 8192);
  };

  f32x4 acc[8][4];
  #pragma unroll
  for (int m = 0; m < 8; ++m)
    #pragma unroll
    for (int n = 0; n < 4; ++n)
      acc[m][n] = (f32x4){0.f, 0.f, 0.f, 0.f};

  short8 af[4][2];   // current A-half fragments (4 m x 2 kk)
  short8 bfr[4][2];  // both B halves resident (4 n x 2 kk)

  auto loadA = [&](int qm, int buf) {
    const char* p = lds + buf * 65536 + qm * 16384 + (wr * 64 + l15) * 128;
    #pragma unroll
    for (int mi = 0; mi < 4; ++mi)
      #pragma unroll
      for (int kk = 0; kk < 2; ++kk)
        af[mi][kk] = *(const short8*)(p + mi * 2048 + ((((kk << 2) | khi) ^ rx) << 4));
  };
  auto loadB = [&](int qn, int buf) {
    const char* p = lds + buf * 65536 + 32768 + qn * 16384 + (wc * 32 + l15) * 128;
    #pragma unroll
    for (int ni = 0; ni < 2; ++ni)
      #pragma unroll
      for (int kk = 0; kk < 2; ++kk)
        bfr[qn * 2 + ni][kk] = *(const short8*)(p + ni * 2048 + ((((kk << 2) | khi) ^ rx) << 4));
  };
  auto mfma8 = [&](int qm, int qn) {
    #pragma unroll
    for (int mi = 0; mi < 4; ++mi)
      #pragma unroll
      for (int ni = 0; ni < 2; ++ni)
        #pragma unroll
        for (int kk = 0; kk < 2; ++kk)
          acc[qm * 4 + mi][qn * 2 + ni] = __builtin_amdgcn_mfma_f32_16x16x32_bf16(
              af[mi][kk], bfr[qn * 2 + ni][kk], acc[qm * 4 + mi][qn * 2 + ni], 0, 0, 0);
  };

  #define BAR() __builtin_amdgcn_s_barrier()
  #define W6() asm volatile("s_waitcnt vmcnt(6)" ::: "memory")
  #define W2() asm volatile("s_waitcnt vmcnt(2)" ::: "memory")
  #define W0() asm volatile("s_waitcnt vmcnt(0)" ::: "memory")

  // prologue: tile 0, order A0,B0,B1,A1 (8 loads); need first 6 done
  stage(Abase, 0, 0, 0, 0);
  stage(Bbase, 0, 1, 0, 0);
  stage(Bbase, 1, 1, 0, 0);
  stage(Abase, 1, 0, 0, 0);
  W2(); BAR();   // A0,B0,B1 of t0 resident (all waves)

  const int NT = K >> 6;
  for (int t = 0; t < NT; ++t) {
    const int buf = t & 1, nbuf = buf ^ 1;
    const bool st = (t + 1 < NT);
    const int k0n = (t + 1) << 6;
    // ---- phase A: A0 x {B0,B1} ----
    loadA(0, buf); loadB(0, buf); loadB(1, buf);      // 16 ds_read_b128
    if (st) {
      stage(Abase, 0, 0, k0n, nbuf);
      stage(Bbase, 0, 1, k0n, nbuf);
      stage(Bbase, 1, 1, k0n, nbuf);
    }
    __builtin_amdgcn_s_setprio(1); mfma8(0, 0); mfma8(0, 1); __builtin_amdgcn_s_setprio(0);
    if (st) { W6(); } else { W0(); }   // A1(t) resident
    BAR();
    // ---- phase B: A1 x {B0,B1} ----
    loadA(1, buf);                                    // 8 ds_read_b128
    if (st) stage(Abase, 1, 0, k0n, nbuf);
    __builtin_amdgcn_s_setprio(1); mfma8(1, 0); mfma8(1, 1); __builtin_amdgcn_s_setprio(0);
    if (st) { W2(); BAR(); }           // A0,B0,B1 of t+1 resident
  }
  #undef BAR
  #undef W6
  #undef W2
  #undef W0

  // ---- epilogue: bias (+ReLU) and store ----
  const float* be = bias + (size_t)e * N + (size_t)tn * 256;
  const size_t cbase = ((size_t)e * Mr + (size_t)tm * 256) * N + (size_t)tn * 256;
  __hip_bfloat16* C16 = (__hip_bfloat16*)Cv + cbase;
  float* C32 = (float*)Cv + cbase;
  #pragma unroll
  for (int n = 0; n < 4; ++n) {
    const int colL = (n >> 1) * 128 + wc * 32 + (n & 1) * 16 + l15;
    const float bv = be[colL];
    #pragma unroll
    for (int m = 0; m < 8; ++m) {
      const int rowL = (m >> 2) * 128 + wr * 64 + (m & 3) * 16 + khi * 4;
      #pragma unroll
      for (int j = 0; j < 4; ++j) {
        float v = acc[m][n][j] + bv;
        if (RELU) v = fmaxf(v, 0.f);
        if (OUTBF16) C16[(size_t)(rowL + j) * N + colL] = __float2bfloat16(v);
        else         C32[(size_t)(rowL + j) * N + colL] = v;
      }
    }
  }
}

// ---------------- combine: y[s] = sum_k gw * eo[flat]  (eo is bf16) ----------------
__global__ __launch_bounds__(256) void combine_kernel(
    const __hip_bfloat16* __restrict__ eo, const int* __restrict__ gflat,
    const float* __restrict__ gw, float* __restrict__ y)
{
  const int s = blockIdx.x;
  const int f0 = gflat[s * 2 + 0], f1 = gflat[s * 2 + 1];
  const float g0 = gw[s * 2 + 0], g1 = gw[s * 2 + 1];
  const int c = threadIdx.x * 4;
  ushort4 a4 = *(const ushort4*)&eo[(size_t)f0 * MDIM + c];
  ushort4 b4 = *(const ushort4*)&eo[(size_t)f1 * MDIM + c];
  const __hip_bfloat16* ap = (const __hip_bfloat16*)&a4;
  const __hip_bfloat16* bp = (const __hip_bfloat16*)&b4;
  float4 r;
  r.x = g0 * __bfloat162float(ap[0]) + g1 * __bfloat162float(bp[0]);
  r.y = g0 * __bfloat162float(ap[1]) + g1 * __bfloat162float(bp[1]);
  r.z = g0 * __bfloat162float(ap[2]) + g1 * __bfloat162float(bp[2]);
  r.w = g0 * __bfloat162float(ap[3]) + g1 * __bfloat162float(bp[3]);
  *(float4*)&y[(size_t)s * MDIM + c] = r;
}

extern "C" void kernel_launch(void* const* d_in, const int* in_sizes, int n_in,
                              void* d_out, int out_size, void* d_ws, size_t ws_size,
                              hipStream_t stream)
{
  (void)in_sizes; (void)n_in; (void)out_size; (void)ws_size;
  const float* x  = (const float*)d_in[0];
  const float* wg = (const float*)d_in[1];
  const float* w1 = (const float*)d_in[2];
  const float* b1 = (const float*)d_in[3];
  const float* w2 = (const float*)d_in[4];
  const float* b2 = (const float*)d_in[5];
  float* y = (float*)d_out;
  float* lloss = y + (size_t)S_TOK * MDIM;

  char* ws = (char*)d_ws;
  __hip_bfloat16* w1t  = (__hip_bfloat16*)(ws);                  // 64 MB  [E][H][M]
  __hip_bfloat16* w2t  = (__hip_bfloat16*)(ws + (64ull << 20));  // 64 MB  [E][M][H]
  __hip_bfloat16* dbuf = (__hip_bfloat16*)(ws + (128ull << 20)); // 32 MB  [E*CAP][M]
  __hip_bfloat16* hbuf = (__hip_bfloat16*)(ws + (160ull << 20)); // 128 MB [E][CAP][H]
  __hip_bfloat16* eo = (__hip_bfloat16*)(ws + (288ull << 20));   // 32 MB  [E*CAP][M] bf16
  char* small = ws + (352ull << 20);
  float* gates_full = (float*)(small);                 // 256 KB
  int*   topk  = (int*)  (small + 262144);             // 64 KB
  float* gnorm = (float*)(small + 262144 + 65536);     // 64 KB
  int*   gflat = (int*)  (small + 262144 + 2 * 65536); // 64 KB
  float* gwv   = (float*)(small + 262144 + 3 * 65536); // 64 KB
  int*   s2t   = (int*)  (small + 262144 + 4 * 65536); // 64 KB

  transpose_cvt_kernel<<<dim3(HDIM / 64, MDIM / 64, NEXP), 256, 0, stream>>>(w1, w1t, MDIM, HDIM);
  transpose_cvt_kernel<<<dim3(MDIM / 64, HDIM / 64, NEXP), 256, 0, stream>>>(w2, w2t, HDIM, MDIM);
  gate_kernel<<<S_TOK / 4, 256, 0, stream>>>(x, wg, gates_full, topk, gnorm);
  scan_kernel<<<1, 1024, 0, stream>>>(topk, gnorm, gates_full, gflat, gwv, s2t, lloss);
  dispatch_kernel<<<NEXP * CAP, 256, 0, stream>>>(x, s2t, dbuf);
  // GEMM1: per expert M=2048, N=4096, K=1024 -> 8x16 tiles x 8 experts = 1024 wg
  gemm256_kernel<1, 1><<<1024, 512, 0, stream>>>(
      dbuf, w1t, b1, (void*)hbuf, CAP, HDIM, MDIM, 16, 128, 1024);
  // GEMM2: per expert M=2048, N=1024, K=4096 -> 8x4 tiles x 8 experts = 256 wg
  gemm256_kernel<0, 1><<<256, 512, 0, stream>>>(
      hbuf, w2t, b2, (void*)eo, CAP, MDIM, HDIM, 4, 32, 256);
  combine_kernel<<<S_TOK, 256, 0, stream>>>(eo, gflat, gwv, y);
}